// Round 3
// baseline (29.289 us; speedup 1.0000x reference)
//
#include <hip/hip_runtime.h>

#define FM_ROWS 16384
#define FM_NFEAT 50
#define FM_NDIM 17          // 16 embedding dims + 1 first-order column
#define ROWS_PER_BLOCK 15   // 15 rows x 17 dims = 255 active threads of 256
#define BLOCK 256

__global__ __launch_bounds__(BLOCK) void FmLayer_14594298871894_kernel(
    const int* __restrict__ feat_index,   // [FM_ROWS][FM_NFEAT]
    const float* __restrict__ table,      // [1e6][FM_NDIM]
    float* __restrict__ out)              // [FM_ROWS][FM_NDIM]
{
    __shared__ int sidx[ROWS_PER_BLOCK * FM_NFEAT];   // 750 ints = 3 KB

    const int tid  = threadIdx.x;
    const int row0 = blockIdx.x * ROWS_PER_BLOCK;
    const int nrows = min(ROWS_PER_BLOCK, FM_ROWS - row0);
    const int nidx  = nrows * FM_NFEAT;

    // Cooperative, coalesced stage of this block's indices into LDS.
    for (int i = tid; i < nidx; i += BLOCK)
        sidx[i] = feat_index[row0 * FM_NFEAT + i];
    __syncthreads();

    const int rl = tid / FM_NDIM;          // local row 0..14
    const int d  = tid - rl * FM_NDIM;     // dim 0..16
    if (rl >= nrows) return;

    const int* __restrict__ ip = sidx + rl * FM_NFEAT;

    float s = 0.0f;   // sum of x
    float q = 0.0f;   // sum of x^2

    // NT-hinted gathers: table lines are touched ~1.5x per launch (random),
    // so L1 allocation is useless; `nt` tests whether TCP allocation/miss-queue
    // behavior was limiting. Line traffic unchanged.
    #pragma unroll
    for (int f0 = 0; f0 < FM_NFEAT; f0 += 25) {
        float x[25];
        #pragma unroll
        for (int j = 0; j < 25; ++j) {
            const float* p = table + (size_t)(ip[f0 + j] * FM_NDIM + d);
            x[j] = __builtin_nontemporal_load(p);
        }
        #pragma unroll
        for (int j = 0; j < 25; ++j) { s += x[j]; q = fmaf(x[j], x[j], q); }
    }

    if (d == 16) {
        out[(row0 + rl) * FM_NDIM] = s;                          // first_order -> col 0
    } else {
        out[(row0 + rl) * FM_NDIM + 1 + d] = 0.5f * (s * s - q); // second_order -> cols 1..16
    }
}

extern "C" void kernel_launch(void* const* d_in, const int* in_sizes, int n_in,
                              void* d_out, int out_size, void* d_ws, size_t ws_size,
                              hipStream_t stream) {
    const int*   feat_index = (const int*)d_in[0];   // 16384*50 int32
    const float* table      = (const float*)d_in[1]; // 1e6*17 float32
    float*       out        = (float*)d_out;         // 16384*17 float32

    const int grid = (FM_ROWS + ROWS_PER_BLOCK - 1) / ROWS_PER_BLOCK;  // 1093
    FmLayer_14594298871894_kernel<<<grid, BLOCK, 0, stream>>>(feat_index, table, out);
}